// Round 15
// baseline (4410.009 us; speedup 1.0000x reference)
//
#include <hip/hip_runtime.h>
#include <stdint.h>

// Problem dims
#define Hh 256                 // hidden
#define Sd 128                 // batch (seq positions)
#define Nt 512                 // time steps per pass
#define NPASS 3
#define TSTEPS (NPASS*Nt)      // 1536
#define RBLK 16                // batch rows per block
#define POIS 0x7F80u           // bf16 +inf: |h|<1 so never a real h value
#define LEAD 192               // max L0 lead over L1; with 16-step cadence <= 208 < 256

typedef float f32x4 __attribute__((ext_vector_type(4)));
typedef __bf16 bf16x8 __attribute__((ext_vector_type(8)));
typedef unsigned short u16x8 __attribute__((ext_vector_type(8)));
typedef unsigned long long ull;
typedef ull ull2 __attribute__((ext_vector_type(2)));

#define HBUF_ELEMS ((size_t)Nt*Sd*Hh)            // ushorts per layer h-ring
#define WPACK_OFF  (2ull*HBUF_ELEMS*2)           // 67,108,864 B
#define FLAGS_OFF  (WPACK_OFF + 2097152ull)      // +2MB packed weights

__device__ __forceinline__ unsigned short f2bf(float f) {
  unsigned u = __builtin_bit_cast(unsigned, f);
  u += 0x7FFFu + ((u >> 16) & 1u);               // RNE
  return (unsigned short)(u >> 16);
}
// fast pack: v_cvt_pk_bf16_f32 x2 (RNE, no builtin on gfx950 -> inline asm)
__device__ __forceinline__ ull pk4(float a, float b, float c, float d) {
  unsigned lo, hi;
  asm("v_cvt_pk_bf16_f32 %0, %1, %2" : "=v"(lo) : "v"(a), "v"(b));
  asm("v_cvt_pk_bf16_f32 %0, %1, %2" : "=v"(hi) : "v"(c), "v"(d));
  return (ull)lo | ((ull)hi << 32);
}
__device__ __forceinline__ bool hasPois(ull v) {
  return ((unsigned short)(v)       == (unsigned short)POIS) |
         ((unsigned short)(v >> 16) == (unsigned short)POIS) |
         ((unsigned short)(v >> 32) == (unsigned short)POIS) |
         ((unsigned short)(v >> 48) == (unsigned short)POIS);
}
// Relaxed agent-scope (cross-XCD coherent) helpers — no fences anywhere.
__device__ __forceinline__ ull ld8(const void* p) {
  return __hip_atomic_load((ull*)p, __ATOMIC_RELAXED, __HIP_MEMORY_SCOPE_AGENT);
}
__device__ __forceinline__ void st8c(void* p, ull v) {
  __hip_atomic_store((ull*)p, v, __ATOMIC_RELAXED, __HIP_MEMORY_SCOPE_AGENT);
}
__device__ __forceinline__ void poll2(const ull* p, ull& a0, ull& a1) {
  while (hasPois(a0) | hasPois(a1)) {
    __builtin_amdgcn_s_sleep(1);
    if (hasPois(a0)) a0 = ld8(p);
    if (hasPois(a1)) a1 = ld8(p + 1);
  }
}
// sleep-free variant: each retry costs one RT; no 64-cy sleep quantization
__device__ __forceinline__ void poll2f(const ull* p, ull& a0, ull& a1) {
  while (hasPois(a0) | hasPois(a1)) {
    if (hasPois(a0)) a0 = ld8(p);
    if (hasPois(a1)) a1 = ld8(p + 1);
  }
}
// LDS-only barrier: orders ds ops without draining vmcnt (stores/prefetch
// loads stay in flight across it).
__device__ __forceinline__ void bar_lgkm() {
  __builtin_amdgcn_sched_barrier(0);
  asm volatile("s_waitcnt lgkmcnt(0)" ::: "memory");
  __builtin_amdgcn_s_barrier();
  __builtin_amdgcn_sched_barrier(0);
}

// ---------------- weight packing (unchanged, verified) ----------------
// id = l<<16 | g2<<13 | w<<10 | kt<<6 | ln ; 8 bf16 per slot.
// value(j) = W.T[k = kt*32 + (ln>>4)*8 + j][col = (w>>1)*256 + g2*32 + (w&1)*16 + (ln&15)]
__global__ void pack_w(const float* __restrict__ Wih0, const float* __restrict__ Whh0,
                       const float* __restrict__ Wih1, const float* __restrict__ Whh1,
                       unsigned short* __restrict__ wpack) {
  int id = blockIdx.x * 256 + threadIdx.x;       // 131072 total
  int ln = id & 63;
  int kt = (id >> 6) & 15;
  int w  = (id >> 10) & 7;
  int g2 = (id >> 13) & 7;
  int l  = (id >> 16) & 1;
  int col = (w >> 1)*256 + g2*32 + (w & 1)*16 + (ln & 15);
  int k0 = kt*32 + (ln >> 4)*8;
  const float* Wih = l ? Wih1 : Wih0;
  const float* Whh = l ? Whh1 : Whh0;
  const float* src = (k0 < 256) ? (Wih + (size_t)col*256 + k0)
                                : (Whh + (size_t)col*256 + (k0 - 256));
  u16x8 v;
#pragma unroll
  for (int j = 0; j < 8; ++j) v[j] = f2bf(src[j]);
  *(u16x8*)(wpack + (size_t)id * 8) = v;
}

// ---------------- data[0] = x copy ----------------
__global__ void copy_x(const float* __restrict__ x, float* __restrict__ out) {
  int id = blockIdx.x * 256 + threadIdx.x;       // 4,194,304 float4s
  int n  = id >> 13;
  int s  = (id >> 6) & 127;
  int h4 = id & 63;
  const float4 v = *(const float4*)(x + ((size_t)n*Sd + s)*Hh + h4*4);
  *(float4*)(out + ((size_t)n*(Sd*4) + s*4)*Hh + h4*4) = v;
}

// ---------------- ring pre-poison ----------------
__global__ void poison_hbuf(unsigned int* __restrict__ p) {
  size_t i = (size_t)blockIdx.x * 256 + threadIdx.x;   // 4,194,304 x 16B = 64MB
  uint4 v = make_uint4(0x7F807F80u, 0x7F807F80u, 0x7F807F80u, 0x7F807F80u);
  *(uint4*)(p + i*4) = v;
}

// ---------------- persistent pipelined LSTM ----------------
// 128 blocks x 512 threads. b: r=b&7 (rowblock group -> XCD r via %8 round-robin;
// peers at stride 8 share one L2 — load-bearing, R9/R11/R13 mapped this),
// g2=(b>>3)&7, l=(b>>6)&1. R12 structure (best, 2914us) + VALU/poll trims.
__global__ void __launch_bounds__(512) lstm_persist(
    const float* __restrict__ x,
    const float* __restrict__ bih0, const float* __restrict__ bhh0,
    const float* __restrict__ bih1, const float* __restrict__ bhh1,
    const unsigned short* __restrict__ wpack,
    unsigned short* __restrict__ hbuf,
    unsigned int* __restrict__ prog,
    float* __restrict__ out)
{
  const int b = blockIdx.x;
  const int r = b & 7;
  const int g2 = (b >> 3) & 7;
  const int l = (b >> 6) & 1;
  const int tid = threadIdx.x;
  const int ln = tid & 63;
  const int w  = tid >> 6;                 // 0..7: q=w>>1 (gate quadrant), jt=w&1

  __shared__ __align__(16) unsigned short AinB[2][RBLK * 256]; // input operand, dbuf
  __shared__ __align__(16) unsigned short Ah[RBLK * 256];      // hidden operand
  __shared__ float gates[RBLK][132];                           // [row][q*32 + cc], +4 pad

  // weight fragments: 16 ktiles x 4 VGPR = 64 VGPRs, resident all kernel
  bf16x8 B[16];
  {
    const unsigned short* base = wpack + ((size_t)((l*8 + g2)*8 + w)) * 8192 + (size_t)ln * 8;
#pragma unroll
    for (int kt = 0; kt < 16; ++kt) {
      u16x8 u = *(const u16x8*)(base + kt * 512);
      B[kt] = __builtin_bit_cast(bf16x8, u);
    }
  }

  // staging + cell identity: thread -> (row = tid>>5, 16B chunk / h-col = tid&31)
  const int srow = tid >> 5;               // 0..15
  const int cc   = tid & 31;               // 16B chunk (k) == h-col (cell)
  const int s    = r*RBLK + srow;          // global seq row
  const int hcol = g2*32 + cc;             // global h col for cell
  float bias[4];
  {
    const float* bi = l ? bih1 : bih0;
    const float* bh = l ? bhh1 : bhh0;
#pragma unroll
    for (int q = 0; q < 4; ++q) {
      int col = q*256 + g2*32 + cc;
      bias[q] = bi[col] + bh[col];
    }
  }
  float cst = 0.f;

  // MFMA fragment addressing (16B-granular XOR swizzle, matches staging swizzle)
  const int row_f = ln & 15;
  const int kg16  = (ln >> 4) * 16;
  const int swr   = (row_f & 7) << 4;
  const int stAddr = srow*512 + ((cc*16) ^ ((srow & 7) << 4));

  unsigned int* flagL1 = prog + r*8;           // 8 L1 publishers per rowblock
  unsigned int* myFlag = prog + r*8 + g2;
  const unsigned short* hbufL0 = hbuf;
  unsigned short* hbufSelf = hbuf + (size_t)l * HBUF_ELEMS;

  // ---- Ain prefetch registers (2-step-ahead pipeline) ----
  float4 pxa, pxb;                         // L0 sources (x fp32 / out fp32)
  ull pa = 0, pb = 0;                      // L1 source (hbufL0 bf16)
  // ---- staggered early h(T-1) probes: probe1 @phase7, probe2 @end-of-phase8 ----
  ull hpa = 0, hpb = 0;                    // probe 1
  ull h2a = 0, h2b = 0;                    // probe 2 (samples MALL ~300cy later)

  auto writeAin = [&](int buf, ull lo, ull hi) {
    ull2 v = {lo, hi};
    *(ull2*)((char*)AinB[buf] + stAddr) = v;
  };
  // issue global loads for Ain(T2) into regs — NO wait here
  auto prefetchAin = [&](int T2) {
    const int t2 = T2 & 511, p2 = T2 >> 9;
    if (l == 1) {
      const ull* ip = (const ull*)(hbufL0 + ((size_t)t2*Sd + s)*Hh + cc*8);
      pa = ld8(ip); pb = ld8(ip + 1);
    } else if (p2 == 0) {
      const float* xb = x + ((size_t)t2*Sd + s)*Hh + cc*8;
      pxa = *(const float4*)(xb);
      pxb = *(const float4*)(xb + 4);
    } else {
      // data[p2]: written by L1 >=300 steps before L0 reads it (flag-guarded);
      // addresses read exactly once -> no staleness hazard.
      const float* ob = out + ((size_t)t2*(Sd*4) + s*4 + p2)*Hh + cc*8;
      pxa = *(const float4*)(ob);
      pxb = *(const float4*)(ob + 4);
    }
  };
  // convert + LDS-write the prefetched Ain(T1); L1 verifies poison here
  auto consumeAin = [&](int T1) {
    const int buf = T1 & 1;
    if (l == 1) {
      if (hasPois(pa) | hasPois(pb)) {
        const int t1 = T1 & 511;
        const ull* ip = (const ull*)(hbufL0 + ((size_t)t1*Sd + s)*Hh + cc*8);
        poll2f(ip, pa, pb);                 // sleep-free: rare post-warmup
      }
      writeAin(buf, pa, pb);
    } else {
      writeAin(buf, pk4(pxa.x, pxa.y, pxa.z, pxa.w), pk4(pxb.x, pxb.y, pxb.z, pxb.w));
    }
  };

#define MFMA4(BUF, BOFF)                                                            \
  {                                                                                 \
    _Pragma("unroll")                                                               \
    for (int kt = 0; kt < 8; kt += 2) {                                             \
      int off0 = row_f*512 + (( kt     *64 + kg16) ^ swr);                          \
      int off1 = row_f*512 + (((kt + 1)*64 + kg16) ^ swr);                          \
      u16x8 a0 = *(const u16x8*)((const char*)(BUF) + off0);                        \
      u16x8 a1 = *(const u16x8*)((const char*)(BUF) + off1);                        \
      acc0 = __builtin_amdgcn_mfma_f32_16x16x32_bf16(                               \
               __builtin_bit_cast(bf16x8, a0), B[BOFF + kt],     acc0, 0,0,0);      \
      acc1 = __builtin_amdgcn_mfma_f32_16x16x32_bf16(                               \
               __builtin_bit_cast(bf16x8, a1), B[BOFF + kt + 1], acc1, 0,0,0);      \
    }                                                                               \
  }

  // ---- prologue: stage Ain(0) directly, prefetch Ain(1), MFMA input-part(0) ----
  f32x4 acc0 = {0.f,0.f,0.f,0.f}, acc1 = {0.f,0.f,0.f,0.f};
  if (l == 1) {
    const ull* ip = (const ull*)(hbufL0 + (size_t)s*Hh + cc*8);
    ull a0 = ld8(ip), a1 = ld8(ip + 1);
    poll2(ip, a0, a1);
    writeAin(0, a0, a1);
  } else {
    const float* xb = x + (size_t)s*Hh + cc*8;
    float4 v0 = *(const float4*)(xb), v1 = *(const float4*)(xb + 4);
    writeAin(0, pk4(v0.x, v0.y, v0.z, v0.w), pk4(v1.x, v1.y, v1.z, v1.w));
  }
  prefetchAin(1);
  __syncthreads();
  MFMA4(AinB[0], 0)

  for (int T = 0; T < TSTEPS; ++T) {
    const int p = T >> 9;
    const int t = T & 511;

    // ===== 1: stage Ah = h(T-1). Probe1 -> probe2 fallback -> fresh retry. =====
    if (T > 0) {
      const ull* ap = (const ull*)(hbufSelf + ((size_t)((T - 1) & 511)*Sd + s)*Hh + cc*8);
      ull a0 = hpa, a1 = hpb;
      if (hasPois(a0) | hasPois(a1)) {
        // fall back to the later-issued probe (already in flight; no new RT)
        if (hasPois(a0)) a0 = h2a;
        if (hasPois(a1)) a1 = h2b;
        while (hasPois(a0) | hasPois(a1)) {   // sleep-free fresh retries
          if (hasPois(a0)) a0 = ld8(ap);
          if (hasPois(a1)) a1 = ld8(ap + 1);
        }
      }
      ull2 v2 = {a0, a1};
      *(ull2*)((char*)Ah + stAddr) = v2;
    } else {
      ull2 v2 = {0ull, 0ull};
      *(ull2*)((char*)Ah + stAddr) = v2;
    }
    // ===== 2: Ain(T+1) from prefetch regs -> LDS (other buffer) =====
    if (T + 1 < TSTEPS) consumeAin(T + 1);
    // ===== 3: L0 lead throttle, every 16 steps =====
    if (l == 0 && (T & 15) == 0 && tid < 8) {
      int need = T - LEAD;
      if (need > 0)
        while ((int)__hip_atomic_load(flagL1 + tid, __ATOMIC_RELAXED, __HIP_MEMORY_SCOPE_AGENT) < need)
          __builtin_amdgcn_s_sleep(1);
    }
    bar_lgkm();                                         // barrier 1 (LDS-only)

    // ===== 4: hidden-part MFMAs (acc already holds input-part of T) =====
    if (T > 0) MFMA4(Ah, 8)

    // gates -> LDS (C layout: col=lane&15, row=(lane>>4)*4+j)
    {
      const int colb = (w >> 1)*32 + (w & 1)*16 + (ln & 15);
      const int rowb = (ln >> 4)*4;
#pragma unroll
      for (int j = 0; j < 4; ++j)
        gates[rowb + j][colb] = acc0[j] + acc1[j];
    }
    bar_lgkm();                                         // barrier 2 (LDS-only)

    // ===== 5: LSTM cell; packed coherent stores (producer never waits) =====
    {
      float G0 = gates[srow][cc]      + bias[0];
      float G1 = gates[srow][32 + cc] + bias[1];
      float G2 = gates[srow][64 + cc] + bias[2];
      float G3 = gates[srow][96 + cc] + bias[3];
      float gi = 1.f/(1.f + __expf(-G0));
      float gf = 1.f/(1.f + __expf(-G1));
      float gg = 1.f - 2.f/(1.f + __expf(2.f*G2));
      float go = 1.f/(1.f + __expf(-G3));
      cst = gf*cst + gi*gg;
      float th = 1.f - 2.f/(1.f + __expf(2.f*cst));
      float hv = go*th;
      float h1 = __shfl_down(hv, 1);
      float h2 = __shfl_down(hv, 2);
      float h3 = __shfl_down(hv, 3);
      if ((cc & 3) == 0) {
        st8c(hbufSelf + ((size_t)t*Sd + s)*Hh + hcol, pk4(hv, h1, h2, h3));
        // re-poison slot reused 256 steps from now (all lag bounds < 254)
        st8c(hbufSelf + ((size_t)((T + 256) & 511)*Sd + s)*Hh + hcol,
             0x7F807F807F807F80ull);
      }
      if (l == 1 && (cc & 1) == 0) {
        ull o01 = ((ull)__builtin_bit_cast(unsigned, hv))
                | ((ull)__builtin_bit_cast(unsigned, h1) << 32);
        st8c(out + ((size_t)t*(Sd*4) + s*4 + (p + 1))*Hh + hcol, o01);
      }
    }
    // ===== 6: flag publish (no drain — out-slack >=300 steps) =====
    if (l == 1 && (T & 15) == 15 && tid == 0)
      __hip_atomic_store(myFlag, (unsigned)(T + 1), __ATOMIC_RELAXED, __HIP_MEMORY_SCOPE_AGENT);
    // ===== 7: early h(T) probe1 FIRST (phase 1 blocks on it; in-order VMEM
    //          queue -> issue before the Ain prefetch), then Ain(T+2) =====
    const ull* apEarly = (const ull*)(hbufSelf + ((size_t)(T & 511)*Sd + s)*Hh + cc*8);
    if (T + 1 < TSTEPS) {
      hpa = ld8(apEarly);
      hpb = ld8(apEarly + 1);
    }
    if (T + 2 < TSTEPS) prefetchAin(T + 2);
    // ===== 8: input-part MFMAs of step T+1, then probe2 (pinned after MFMAs:
    //          samples the MALL ~300cy later than probe1) =====
    acc0 = (f32x4){0.f,0.f,0.f,0.f};
    acc1 = (f32x4){0.f,0.f,0.f,0.f};
    if (T + 1 < TSTEPS) {
      MFMA4(AinB[(T + 1) & 1], 0)
      __builtin_amdgcn_sched_barrier(0);
      h2a = ld8(apEarly);
      h2b = ld8(apEarly + 1);
    }
  }
}

extern "C" void kernel_launch(void* const* d_in, const int* in_sizes, int n_in,
                              void* d_out, int out_size, void* d_ws, size_t ws_size,
                              hipStream_t stream) {
  const float* x    = (const float*)d_in[0];
  const float* Wih0 = (const float*)d_in[1];
  const float* Whh0 = (const float*)d_in[2];
  const float* bih0 = (const float*)d_in[3];
  const float* bhh0 = (const float*)d_in[4];
  const float* Wih1 = (const float*)d_in[5];
  const float* Whh1 = (const float*)d_in[6];
  const float* bih1 = (const float*)d_in[7];
  const float* bhh1 = (const float*)d_in[8];
  float* out = (float*)d_out;
  char* ws = (char*)d_ws;

  if (ws_size < FLAGS_OFF + 4096) return;  // need ~69 MB scratch

  unsigned short* hbuf  = (unsigned short*)ws;
  unsigned short* wpack = (unsigned short*)(ws + WPACK_OFF);
  unsigned int*   prog  = (unsigned int*)(ws + FLAGS_OFF);

  (void)hipMemsetAsync(prog, 0, 1024, stream);
  hipLaunchKernelGGL(poison_hbuf, dim3(16384), dim3(256), 0, stream, (unsigned int*)hbuf);
  hipLaunchKernelGGL(pack_w, dim3(512), dim3(256), 0, stream, Wih0, Whh0, Wih1, Whh1, wpack);
  hipLaunchKernelGGL(copy_x, dim3(16384), dim3(256), 0, stream, x, out);
  hipLaunchKernelGGL(lstm_persist, dim3(128), dim3(512), 0, stream,
                     x, bih0, bhh0, bih1, bhh1, wpack, hbuf, prog, out);
}

// Round 16
// 2909.084 us; speedup vs baseline: 1.5159x; 1.5159x over previous
//
#include <hip/hip_runtime.h>
#include <stdint.h>

// Problem dims
#define Hh 256                 // hidden
#define Sd 128                 // batch (seq positions)
#define Nt 512                 // time steps per pass
#define NPASS 3
#define TSTEPS (NPASS*Nt)      // 1536
#define RBLK 16                // batch rows per block
#define POIS 0x7F80u           // bf16 +inf: |h|<1 so never a real h value
#define LEAD 192               // max L0 lead over L1; with 16-step cadence <= 208 < 256

typedef float f32x4 __attribute__((ext_vector_type(4)));
typedef __bf16 bf16x8 __attribute__((ext_vector_type(8)));
typedef unsigned short u16x8 __attribute__((ext_vector_type(8)));
typedef unsigned long long ull;
typedef ull ull2 __attribute__((ext_vector_type(2)));

#define HBUF_ELEMS ((size_t)Nt*Sd*Hh)            // ushorts per layer h-ring
#define WPACK_OFF  (2ull*HBUF_ELEMS*2)           // 67,108,864 B
#define FLAGS_OFF  (WPACK_OFF + 2097152ull)      // +2MB packed weights

__device__ __forceinline__ unsigned short f2bf(float f) {
  unsigned u = __builtin_bit_cast(unsigned, f);
  u += 0x7FFFu + ((u >> 16) & 1u);               // RNE
  return (unsigned short)(u >> 16);
}
__device__ __forceinline__ ull pk4(float a, float b, float c, float d) {
  return (ull)f2bf(a) | ((ull)f2bf(b) << 16) | ((ull)f2bf(c) << 32) | ((ull)f2bf(d) << 48);
}
__device__ __forceinline__ bool hasPois(ull v) {
  return ((unsigned short)(v)       == (unsigned short)POIS) |
         ((unsigned short)(v >> 16) == (unsigned short)POIS) |
         ((unsigned short)(v >> 32) == (unsigned short)POIS) |
         ((unsigned short)(v >> 48) == (unsigned short)POIS);
}
// Relaxed agent-scope (cross-XCD coherent) helpers — no fences anywhere.
__device__ __forceinline__ ull ld8(const void* p) {
  return __hip_atomic_load((ull*)p, __ATOMIC_RELAXED, __HIP_MEMORY_SCOPE_AGENT);
}
__device__ __forceinline__ void st8c(void* p, ull v) {
  __hip_atomic_store((ull*)p, v, __ATOMIC_RELAXED, __HIP_MEMORY_SCOPE_AGENT);
}
__device__ __forceinline__ void poll2(const ull* p, ull& a0, ull& a1) {
  while (hasPois(a0) | hasPois(a1)) {
    __builtin_amdgcn_s_sleep(1);
    if (hasPois(a0)) a0 = ld8(p);
    if (hasPois(a1)) a1 = ld8(p + 1);
  }
}
// LDS-only barrier: orders ds ops without draining vmcnt (stores/prefetch
// loads stay in flight across it).
__device__ __forceinline__ void bar_lgkm() {
  __builtin_amdgcn_sched_barrier(0);
  asm volatile("s_waitcnt lgkmcnt(0)" ::: "memory");
  __builtin_amdgcn_s_barrier();
  __builtin_amdgcn_sched_barrier(0);
}

// ---------------- weight packing (unchanged, verified) ----------------
// id = l<<16 | g2<<13 | w<<10 | kt<<6 | ln ; 8 bf16 per slot.
// value(j) = W.T[k = kt*32 + (ln>>4)*8 + j][col = (w>>1)*256 + g2*32 + (w&1)*16 + (ln&15)]
__global__ void pack_w(const float* __restrict__ Wih0, const float* __restrict__ Whh0,
                       const float* __restrict__ Wih1, const float* __restrict__ Whh1,
                       unsigned short* __restrict__ wpack) {
  int id = blockIdx.x * 256 + threadIdx.x;       // 131072 total
  int ln = id & 63;
  int kt = (id >> 6) & 15;
  int w  = (id >> 10) & 7;
  int g2 = (id >> 13) & 7;
  int l  = (id >> 16) & 1;
  int col = (w >> 1)*256 + g2*32 + (w & 1)*16 + (ln & 15);
  int k0 = kt*32 + (ln >> 4)*8;
  const float* Wih = l ? Wih1 : Wih0;
  const float* Whh = l ? Whh1 : Whh0;
  const float* src = (k0 < 256) ? (Wih + (size_t)col*256 + k0)
                                : (Whh + (size_t)col*256 + (k0 - 256));
  u16x8 v;
#pragma unroll
  for (int j = 0; j < 8; ++j) v[j] = f2bf(src[j]);
  *(u16x8*)(wpack + (size_t)id * 8) = v;
}

// ---------------- data[0] = x copy ----------------
__global__ void copy_x(const float* __restrict__ x, float* __restrict__ out) {
  int id = blockIdx.x * 256 + threadIdx.x;       // 4,194,304 float4s
  int n  = id >> 13;
  int s  = (id >> 6) & 127;
  int h4 = id & 63;
  const float4 v = *(const float4*)(x + ((size_t)n*Sd + s)*Hh + h4*4);
  *(float4*)(out + ((size_t)n*(Sd*4) + s*4)*Hh + h4*4) = v;
}

// ---------------- ring pre-poison ----------------
__global__ void poison_hbuf(unsigned int* __restrict__ p) {
  size_t i = (size_t)blockIdx.x * 256 + threadIdx.x;   // 4,194,304 x 16B = 64MB
  uint4 v = make_uint4(0x7F807F80u, 0x7F807F80u, 0x7F807F80u, 0x7F807F80u);
  *(uint4*)(p + i*4) = v;
}

// ---------------- persistent pipelined LSTM ----------------
// 128 blocks x 512 threads. b: r=b&7 (rowblock group -> XCD r via %8 round-robin;
// peers at stride 8 share one L2 for the cached x/out read paths — load-bearing,
// verified by R9/R11 FETCH explosions when broken), g2=(b>>3)&7, l=(b>>6)&1.
__global__ void __launch_bounds__(512) lstm_persist(
    const float* __restrict__ x,
    const float* __restrict__ bih0, const float* __restrict__ bhh0,
    const float* __restrict__ bih1, const float* __restrict__ bhh1,
    const unsigned short* __restrict__ wpack,
    unsigned short* __restrict__ hbuf,
    unsigned int* __restrict__ prog,
    float* __restrict__ out)
{
  const int b = blockIdx.x;
  const int r = b & 7;
  const int g2 = (b >> 3) & 7;
  const int l = (b >> 6) & 1;
  const int tid = threadIdx.x;
  const int ln = tid & 63;
  const int w  = tid >> 6;                 // 0..7: q=w>>1 (gate quadrant), jt=w&1

  __shared__ __align__(16) unsigned short AinB[2][RBLK * 256]; // input operand, dbuf
  __shared__ __align__(16) unsigned short Ah[RBLK * 256];      // hidden operand
  __shared__ float gates[RBLK][132];                           // [row][q*32 + cc], +4 pad

  // weight fragments: 16 ktiles x 4 VGPR = 64 VGPRs, resident all kernel
  bf16x8 B[16];
  {
    const unsigned short* base = wpack + ((size_t)((l*8 + g2)*8 + w)) * 8192 + (size_t)ln * 8;
#pragma unroll
    for (int kt = 0; kt < 16; ++kt) {
      u16x8 u = *(const u16x8*)(base + kt * 512);
      B[kt] = __builtin_bit_cast(bf16x8, u);
    }
  }

  // staging + cell identity: thread -> (row = tid>>5, 16B chunk / h-col = tid&31)
  const int srow = tid >> 5;               // 0..15
  const int cc   = tid & 31;               // 16B chunk (k) == h-col (cell)
  const int s    = r*RBLK + srow;          // global seq row
  const int hcol = g2*32 + cc;             // global h col for cell
  float bias[4];
  {
    const float* bi = l ? bih1 : bih0;
    const float* bh = l ? bhh1 : bhh0;
#pragma unroll
    for (int q = 0; q < 4; ++q) {
      int col = q*256 + g2*32 + cc;
      bias[q] = bi[col] + bh[col];
    }
  }
  float cst = 0.f;

  // MFMA fragment addressing (16B-granular XOR swizzle, matches staging swizzle)
  const int row_f = ln & 15;
  const int kg16  = (ln >> 4) * 16;
  const int swr   = (row_f & 7) << 4;
  const int stAddr = srow*512 + ((cc*16) ^ ((srow & 7) << 4));

  unsigned int* flagL1 = prog + r*8;           // 8 L1 publishers per rowblock
  unsigned int* myFlag = prog + r*8 + g2;
  const unsigned short* hbufL0 = hbuf;
  unsigned short* hbufSelf = hbuf + (size_t)l * HBUF_ELEMS;

  // ---- Ain prefetch registers (2-step-ahead pipeline) ----
  float4 pxa, pxb;                         // L0 sources (x fp32 / out fp32)
  ull pa = 0, pb = 0;                      // L1 source (hbufL0 bf16)
  // ---- staggered early h(T-1) probes: probe1 @phase7, probe2 @end-of-phase8 ----
  ull hpa = 0, hpb = 0;                    // probe 1
  ull h2a = 0, h2b = 0;                    // probe 2 (samples MALL ~300cy later)

  auto writeAin = [&](int buf, ull lo, ull hi) {
    ull2 v = {lo, hi};
    *(ull2*)((char*)AinB[buf] + stAddr) = v;
  };
  // issue global loads for Ain(T2) into regs — NO wait here
  auto prefetchAin = [&](int T2) {
    const int t2 = T2 & 511, p2 = T2 >> 9;
    if (l == 1) {
      const ull* ip = (const ull*)(hbufL0 + ((size_t)t2*Sd + s)*Hh + cc*8);
      pa = ld8(ip); pb = ld8(ip + 1);
    } else if (p2 == 0) {
      const float* xb = x + ((size_t)t2*Sd + s)*Hh + cc*8;
      pxa = *(const float4*)(xb);
      pxb = *(const float4*)(xb + 4);
    } else {
      // data[p2]: written by L1 >=300 steps before L0 reads it (flag-guarded);
      // addresses read exactly once -> no staleness hazard.
      const float* ob = out + ((size_t)t2*(Sd*4) + s*4 + p2)*Hh + cc*8;
      pxa = *(const float4*)(ob);
      pxb = *(const float4*)(ob + 4);
    }
  };
  // convert + LDS-write the prefetched Ain(T1); L1 verifies poison here
  auto consumeAin = [&](int T1) {
    const int buf = T1 & 1;
    if (l == 1) {
      if (hasPois(pa) | hasPois(pb)) {
        const int t1 = T1 & 511;
        const ull* ip = (const ull*)(hbufL0 + ((size_t)t1*Sd + s)*Hh + cc*8);
        poll2(ip, pa, pb);
      }
      writeAin(buf, pa, pb);
    } else {
      writeAin(buf, pk4(pxa.x, pxa.y, pxa.z, pxa.w), pk4(pxb.x, pxb.y, pxb.z, pxb.w));
    }
  };

#define MFMA4(BUF, BOFF)                                                            \
  {                                                                                 \
    _Pragma("unroll")                                                               \
    for (int kt = 0; kt < 8; kt += 2) {                                             \
      int off0 = row_f*512 + (( kt     *64 + kg16) ^ swr);                          \
      int off1 = row_f*512 + (((kt + 1)*64 + kg16) ^ swr);                          \
      u16x8 a0 = *(const u16x8*)((const char*)(BUF) + off0);                        \
      u16x8 a1 = *(const u16x8*)((const char*)(BUF) + off1);                        \
      acc0 = __builtin_amdgcn_mfma_f32_16x16x32_bf16(                               \
               __builtin_bit_cast(bf16x8, a0), B[BOFF + kt],     acc0, 0,0,0);      \
      acc1 = __builtin_amdgcn_mfma_f32_16x16x32_bf16(                               \
               __builtin_bit_cast(bf16x8, a1), B[BOFF + kt + 1], acc1, 0,0,0);      \
    }                                                                               \
  }

  // ---- prologue: stage Ain(0) directly, prefetch Ain(1), MFMA input-part(0) ----
  f32x4 acc0 = {0.f,0.f,0.f,0.f}, acc1 = {0.f,0.f,0.f,0.f};
  if (l == 1) {
    const ull* ip = (const ull*)(hbufL0 + (size_t)s*Hh + cc*8);
    ull a0 = ld8(ip), a1 = ld8(ip + 1);
    poll2(ip, a0, a1);
    writeAin(0, a0, a1);
  } else {
    const float* xb = x + (size_t)s*Hh + cc*8;
    float4 v0 = *(const float4*)(xb), v1 = *(const float4*)(xb + 4);
    writeAin(0, pk4(v0.x, v0.y, v0.z, v0.w), pk4(v1.x, v1.y, v1.z, v1.w));
  }
  prefetchAin(1);
  __syncthreads();
  MFMA4(AinB[0], 0)

  for (int T = 0; T < TSTEPS; ++T) {
    const int p = T >> 9;
    const int t = T & 511;

    // ===== 1: stage Ah = h(T-1). Probe1 -> probe2 fallback -> fresh retry. =====
    if (T > 0) {
      const ull* ap = (const ull*)(hbufSelf + ((size_t)((T - 1) & 511)*Sd + s)*Hh + cc*8);
      ull a0 = hpa, a1 = hpb;
      if (hasPois(a0) | hasPois(a1)) {
        // fall back to the later-issued probe (already in flight; no new RT)
        if (hasPois(a0)) a0 = h2a;
        if (hasPois(a1)) a1 = h2b;
        while (hasPois(a0) | hasPois(a1)) {   // sleep-free fresh retries
          if (hasPois(a0)) a0 = ld8(ap);
          if (hasPois(a1)) a1 = ld8(ap + 1);
        }
      }
      ull2 v2 = {a0, a1};
      *(ull2*)((char*)Ah + stAddr) = v2;
    } else {
      ull2 v2 = {0ull, 0ull};
      *(ull2*)((char*)Ah + stAddr) = v2;
    }
    // ===== 2: Ain(T+1) from prefetch regs -> LDS (other buffer) =====
    if (T + 1 < TSTEPS) consumeAin(T + 1);
    // ===== 3: L0 lead throttle, every 16 steps =====
    if (l == 0 && (T & 15) == 0 && tid < 8) {
      int need = T - LEAD;
      if (need > 0)
        while ((int)__hip_atomic_load(flagL1 + tid, __ATOMIC_RELAXED, __HIP_MEMORY_SCOPE_AGENT) < need)
          __builtin_amdgcn_s_sleep(1);
    }
    bar_lgkm();                                         // barrier 1 (LDS-only)

    // ===== 4: hidden-part MFMAs (acc already holds input-part of T) =====
    if (T > 0) MFMA4(Ah, 8)

    // gates -> LDS (C layout: col=lane&15, row=(lane>>4)*4+j)
    {
      const int colb = (w >> 1)*32 + (w & 1)*16 + (ln & 15);
      const int rowb = (ln >> 4)*4;
#pragma unroll
      for (int j = 0; j < 4; ++j)
        gates[rowb + j][colb] = acc0[j] + acc1[j];
    }
    bar_lgkm();                                         // barrier 2 (LDS-only)

    // ===== 5: LSTM cell; packed coherent stores (producer never waits) =====
    {
      float G0 = gates[srow][cc]      + bias[0];
      float G1 = gates[srow][32 + cc] + bias[1];
      float G2 = gates[srow][64 + cc] + bias[2];
      float G3 = gates[srow][96 + cc] + bias[3];
      float gi = 1.f/(1.f + __expf(-G0));
      float gf = 1.f/(1.f + __expf(-G1));
      float gg = 1.f - 2.f/(1.f + __expf(2.f*G2));
      float go = 1.f/(1.f + __expf(-G3));
      cst = gf*cst + gi*gg;
      float th = 1.f - 2.f/(1.f + __expf(2.f*cst));
      float hv = go*th;
      float h1 = __shfl_down(hv, 1);
      float h2 = __shfl_down(hv, 2);
      float h3 = __shfl_down(hv, 3);
      if ((cc & 3) == 0) {
        st8c(hbufSelf + ((size_t)t*Sd + s)*Hh + hcol, pk4(hv, h1, h2, h3));
        // re-poison slot reused 256 steps from now (all lag bounds < 254)
        st8c(hbufSelf + ((size_t)((T + 256) & 511)*Sd + s)*Hh + hcol,
             0x7F807F807F807F80ull);
      }
      if (l == 1 && (cc & 1) == 0) {
        ull o01 = ((ull)__builtin_bit_cast(unsigned, hv))
                | ((ull)__builtin_bit_cast(unsigned, h1) << 32);
        st8c(out + ((size_t)t*(Sd*4) + s*4 + (p + 1))*Hh + hcol, o01);
      }
    }
    // ===== 6: flag publish (no drain — out-slack >=300 steps) =====
    if (l == 1 && (T & 15) == 15 && tid == 0)
      __hip_atomic_store(myFlag, (unsigned)(T + 1), __ATOMIC_RELAXED, __HIP_MEMORY_SCOPE_AGENT);
    // ===== 7: issue Ain(T+2) prefetch + early h(T) probe1 =====
    if (T + 2 < TSTEPS) prefetchAin(T + 2);
    const ull* apEarly = (const ull*)(hbufSelf + ((size_t)(T & 511)*Sd + s)*Hh + cc*8);
    if (T + 1 < TSTEPS) {
      hpa = ld8(apEarly);
      hpb = ld8(apEarly + 1);
    }
    // ===== 8: input-part MFMAs of step T+1, then probe2 (pinned after MFMAs:
    //          samples the MALL ~300cy later than probe1) =====
    acc0 = (f32x4){0.f,0.f,0.f,0.f};
    acc1 = (f32x4){0.f,0.f,0.f,0.f};
    if (T + 1 < TSTEPS) {
      MFMA4(AinB[(T + 1) & 1], 0)
      __builtin_amdgcn_sched_barrier(0);
      h2a = ld8(apEarly);
      h2b = ld8(apEarly + 1);
    }
  }
}

extern "C" void kernel_launch(void* const* d_in, const int* in_sizes, int n_in,
                              void* d_out, int out_size, void* d_ws, size_t ws_size,
                              hipStream_t stream) {
  const float* x    = (const float*)d_in[0];
  const float* Wih0 = (const float*)d_in[1];
  const float* Whh0 = (const float*)d_in[2];
  const float* bih0 = (const float*)d_in[3];
  const float* bhh0 = (const float*)d_in[4];
  const float* Wih1 = (const float*)d_in[5];
  const float* Whh1 = (const float*)d_in[6];
  const float* bih1 = (const float*)d_in[7];
  const float* bhh1 = (const float*)d_in[8];
  float* out = (float*)d_out;
  char* ws = (char*)d_ws;

  if (ws_size < FLAGS_OFF + 4096) return;  // need ~69 MB scratch

  unsigned short* hbuf  = (unsigned short*)ws;
  unsigned short* wpack = (unsigned short*)(ws + WPACK_OFF);
  unsigned int*   prog  = (unsigned int*)(ws + FLAGS_OFF);

  (void)hipMemsetAsync(prog, 0, 1024, stream);
  hipLaunchKernelGGL(poison_hbuf, dim3(16384), dim3(256), 0, stream, (unsigned int*)hbuf);
  hipLaunchKernelGGL(pack_w, dim3(512), dim3(256), 0, stream, Wih0, Whh0, Wih1, Whh1, wpack);
  hipLaunchKernelGGL(copy_x, dim3(16384), dim3(256), 0, stream, x, out);
  hipLaunchKernelGGL(lstm_persist, dim3(128), dim3(512), 0, stream,
                     x, bih0, bhh0, bih1, bhh1, wpack, hbuf, prog, out);
}